// Round 4
// baseline (667.486 us; speedup 1.0000x reference)
//
#include <hip/hip_runtime.h>

#define LOG2E 1.4426950408889634f

typedef __attribute__((ext_vector_type(8)))  __bf16       bf16x8;
typedef __attribute__((ext_vector_type(16))) float        f32x16;
typedef __attribute__((ext_vector_type(4)))  float        f32x4;
typedef __attribute__((ext_vector_type(4)))  unsigned int u32x4;

#define ROWPAT(g, hi) ((((g)&3)) + 8*((g)>>2) + 4*(hi))

__device__ inline unsigned short f2bf(float f){
  unsigned u = __builtin_bit_cast(unsigned, f);
  u += 0x7FFFu + ((u >> 16) & 1u);
  return (unsigned short)(u >> 16);
}
__device__ inline float bf2f(unsigned short h){
  unsigned u = ((unsigned)h) << 16;
  return __builtin_bit_cast(float, u);
}
__device__ inline unsigned pack2bf(float lo, float hi){
  return (unsigned)f2bf(lo) | ((unsigned)f2bf(hi) << 16);
}
__device__ inline f32x16 zero16(){
  f32x16 z;
  #pragma unroll
  for (int i=0;i<16;i++) z[i]=0.f;
  return z;
}

// ---------------- K0: W (512x512 fp32, [k][n]) -> Wt bf16 [n][k] ----------------
__global__ __launch_bounds__(256) void transpose_w_kernel(const float* __restrict__ W,
                                                          unsigned short* __restrict__ Wt){
  __shared__ unsigned short t[32][33];
  const int n0 = blockIdx.x*32, k0 = blockIdx.y*32;
  const int tx = threadIdx.x & 31, ty = threadIdx.x >> 5;   // ty 0..7
  #pragma unroll
  for (int i=0;i<4;i++){
    int k = ty*4 + i;
    t[k][tx] = f2bf(W[(size_t)(k0+k)*512 + n0+tx]);
  }
  __syncthreads();
  #pragma unroll
  for (int i=0;i<4;i++){
    int n = ty*4+i;
    Wt[(size_t)(n0+n)*512 + k0 + tx] = t[tx][n];
  }
}

// ---------------- K0b: V [bh][l][dh] bf16 -> VT [bh][dh][l] bf16 ----------------
__global__ __launch_bounds__(256) void transpose_v_kernel(const unsigned short* __restrict__ V,
                                                          unsigned short* __restrict__ VT){
  __shared__ unsigned short t[32][33];
  const int bh = blockIdx.z;
  const int l0 = blockIdx.x*32, d0 = blockIdx.y*32;
  const int tx = threadIdx.x & 31, ty = threadIdx.x >> 5;
  const unsigned short* Vb = V + (size_t)bh*2048*64;
  unsigned short* Tb = VT + (size_t)bh*64*2048;
  #pragma unroll
  for (int i=0;i<4;i++){
    int row = ty*4+i;
    t[row][tx] = Vb[(size_t)(l0+row)*64 + d0+tx];
  }
  __syncthreads();
  #pragma unroll
  for (int i=0;i<4;i++){
    int d = ty*4+i;
    Tb[(size_t)(d0+d)*2048 + l0+tx] = t[tx][d];
  }
}

// ---------------- K1: Y[b,h,l,dh] (bf16) = X(8192x512 fp32) @ W + bias ----------------
__global__ __launch_bounds__(256,2) void proj_gemm_kernel(
    const float* __restrict__ X, const unsigned int* __restrict__ Wt, // Wt: [n][k] as uint pairs [512][256]
    const float* __restrict__ bias, unsigned short* __restrict__ Y)
{
  __shared__ unsigned int Al[128][17];
  __shared__ unsigned int Bl[128][17];
  const int n0 = blockIdx.x * 128;
  const int m0 = blockIdx.y * 128;
  const int tid = threadIdx.x;
  const int lane = tid & 63, wave = tid >> 6;
  const int lr = lane & 31, hi = lane >> 5;
  const int wr = wave >> 1, wc = wave & 1;
  const int r = tid & 127, kh = tid >> 7;

  f32x16 acc[2][2];
  acc[0][0]=zero16(); acc[0][1]=zero16(); acc[1][0]=zero16(); acc[1][1]=zero16();

  for (int k0=0; k0<512; k0+=32){
    const float* Xr = X + (size_t)(m0 + r)*512 + k0 + kh*16;
    #pragma unroll
    for (int c=0;c<2;c++){
      f32x4 x0 = *(const f32x4*)(Xr + c*8);
      f32x4 x1 = *(const f32x4*)(Xr + c*8 + 4);
      Al[r][kh*8 + c*4 + 0] = pack2bf(x0[0], x0[1]);
      Al[r][kh*8 + c*4 + 1] = pack2bf(x0[2], x0[3]);
      Al[r][kh*8 + c*4 + 2] = pack2bf(x1[0], x1[1]);
      Al[r][kh*8 + c*4 + 3] = pack2bf(x1[2], x1[3]);
    }
    const unsigned int* Wr = Wt + (size_t)(n0 + r)*256 + (k0>>1) + kh*8;
    #pragma unroll
    for (int c=0;c<8;c++) Bl[r][kh*8 + c] = Wr[c];
    __syncthreads();
    #pragma unroll
    for (int t=0;t<2;t++){
      bf16x8 af[2], bfr[2];
      #pragma unroll
      for (int mt=0;mt<2;mt++){
        u32x4 w;
        #pragma unroll
        for (int j=0;j<4;j++) w[j] = Al[wr*64 + mt*32 + lr][t*8 + hi*4 + j];
        af[mt] = __builtin_bit_cast(bf16x8, w);
      }
      #pragma unroll
      for (int nt=0;nt<2;nt++){
        u32x4 w;
        #pragma unroll
        for (int j=0;j<4;j++) w[j] = Bl[wc*64 + nt*32 + lr][t*8 + hi*4 + j];
        bfr[nt] = __builtin_bit_cast(bf16x8, w);
      }
      #pragma unroll
      for (int mt=0;mt<2;mt++)
        #pragma unroll
        for (int nt=0;nt<2;nt++)
          acc[mt][nt] = __builtin_amdgcn_mfma_f32_32x32x16_bf16(af[mt], bfr[nt], acc[mt][nt], 0,0,0);
    }
    __syncthreads();
  }

  #pragma unroll
  for (int mt=0;mt<2;mt++)
    #pragma unroll
    for (int nt=0;nt<2;nt++){
      const int n = n0 + wc*64 + nt*32 + lr;
      const float bv = bias[n];
      const int h = n >> 6, dh = n & 63;
      #pragma unroll
      for (int g=0; g<16; g++){
        const int m = m0 + wr*64 + mt*32 + ROWPAT(g,hi);
        const int b = m >> 11, l = m & 2047;
        Y[((size_t)(b*8 + h)*2048 + l)*64 + dh] = f2bf(acc[mt][nt][g] + bv);
      }
    }
}

// ---------------- K2: fused relative attention (windowed Srel, 2-pass) ----------------
// grid (64 l-tiles, 32 bh), 512 threads (8 waves). One 32-row q-tile per block.
// Srel band is recomputed per s-iteration into an 18KB LDS window:
//   window covers u = l - s for this iteration, u_rel = lr + 255 - 32*wave - ROWPAT in [0,286].
__global__ __launch_bounds__(512,4) void attn_kernel(
    const unsigned short* __restrict__ Q,
    const unsigned short* __restrict__ Kb,
    const unsigned short* __restrict__ VT,
    const float* __restrict__ E,
    float* __restrict__ attn_w,
    unsigned short* __restrict__ attn_o)
{
  __shared__ unsigned short win[288*32];   // 18 KiB; aliased as f32 for md-merge and pv-reduce
  const int l0 = blockIdx.x * 32;
  const int bh = blockIdx.y;
  const int tid = threadIdx.x;
  const int wave = tid >> 6;
  const int lane = tid & 63;
  const int lr = lane & 31;
  const int hi = lane >> 5;
  const int l  = l0 + lr;                   // this lane's q-row (col of swapped acc)

  // Q fragments (B operand of swapped QK): lane holds q-row l, d = 16t + 8hi + j
  const unsigned short* Qrow = Q + ((size_t)bh*2048 + l)*64;
  bf16x8 qf[4];
  #pragma unroll
  for (int t=0;t<4;t++) qf[t] = *(const bf16x8*)(Qrow + t*16 + hi*8);

  const unsigned short* Krows = Kb + (size_t)bh*2048*64;
  const unsigned short* Vtb   = VT + (size_t)bh*64*2048;

  float m_run = -3e38f, d_run = 0.f;

  // ---- pass 1: per-wave online max + denominator over this wave's s-subset ----
  for (int it=0; it<8; it++){
    const int s0 = it*256 + wave*32;
    const bool has_rel = (it*256 <= l0 + 31);
    if (has_rel){
      __syncthreads();                       // prior window fully consumed
      #pragma unroll 1
      for (int t = wave; t < 9; t += 8){
        const int e0 = 2302 - l0 + it*256 - 32*t - lr;   // = 2047 - u  for this lane's row
        const int e_idx = e0 < 0 ? 0 : (e0 > 2047 ? 2047 : e0);
        const float* Erow = E + (size_t)e_idx*64;
        f32x16 acc = zero16();
        #pragma unroll
        for (int tt=0;tt<4;tt++){
          f32x4 ea = *(const f32x4*)(Erow + tt*16 + hi*8);
          f32x4 eb = *(const f32x4*)(Erow + tt*16 + hi*8 + 4);
          u32x4 w;
          w[0]=pack2bf(ea[0],ea[1]); w[1]=pack2bf(ea[2],ea[3]);
          w[2]=pack2bf(eb[0],eb[1]); w[3]=pack2bf(eb[2],eb[3]);
          bf16x8 ef = __builtin_bit_cast(bf16x8, w);
          acc = __builtin_amdgcn_mfma_f32_32x32x16_bf16(ef, qf[tt], acc, 0,0,0);
        }
        #pragma unroll
        for (int g=0; g<16; g++)
          win[(t*32 + ROWPAT(g,hi))*32 + lr] = f2bf(acc[g]);
      }
      __syncthreads();                       // window ready
    }
    f32x16 acc = zero16();
    const unsigned short* Krow = Krows + (size_t)(s0 + lr)*64;
    #pragma unroll
    for (int t=0;t<4;t++){
      bf16x8 kf = *(const bf16x8*)(Krow + t*16 + hi*8);
      acc = __builtin_amdgcn_mfma_f32_32x32x16_bf16(kf, qf[t], acc, 0,0,0);
    }
    float lg[16];
    #pragma unroll
    for (int g=0; g<16; g++){
      const int rp = ROWPAT(g,hi);
      const int s = s0 + rp;
      const int widx = lr + 255 - 32*wave - rp;
      const float rel = (s <= l) ? bf2f(win[widx*32 + lr]) : 0.f;
      lg[g] = (acc[g] + rel) * 0.125f;
    }
    float mt = lg[0];
    #pragma unroll
    for (int g=1; g<16; g++) mt = fmaxf(mt, lg[g]);
    mt = fmaxf(mt, __shfl_xor(mt, 32, 64));
    float mnew = fmaxf(m_run, mt);
    float ps = 0.f;
    #pragma unroll
    for (int g=0; g<16; g++) ps += exp2f((lg[g]-mnew)*LOG2E);
    ps += __shfl_xor(ps, 32, 64);
    d_run = d_run * exp2f((m_run - mnew)*LOG2E) + ps;
    m_run = mnew;
  }

  // ---- cross-wave merge of softmax stats (window LDS aliased as f32) ----
  __syncthreads();
  float* mdm = (float*)win;
  float* mdd = mdm + 256;
  if (hi == 0){ mdm[wave*32+lr] = m_run; mdd[wave*32+lr] = d_run; }
  __syncthreads();
  float m_tot = mdm[lr];
  #pragma unroll
  for (int w=1; w<8; w++) m_tot = fmaxf(m_tot, mdm[w*32+lr]);
  float d_tot = 0.f;
  #pragma unroll
  for (int w=0; w<8; w++) d_tot += mdd[w*32+lr] * exp2f((mdm[w*32+lr] - m_tot)*LOG2E);
  m_run = m_tot;
  const float inv_d = 1.f / d_tot;

  // ---- pass 2: write attn_w + accumulate partial P.V ----
  f32x16 oacc[2];
  oacc[0]=zero16(); oacc[1]=zero16();
  float* awbase = attn_w + ((size_t)bh*2048 + l)*2048;

  for (int it=0; it<8; it++){
    const int s0 = it*256 + wave*32;
    const bool has_rel = (it*256 <= l0 + 31);
    if (has_rel){
      __syncthreads();
      #pragma unroll 1
      for (int t = wave; t < 9; t += 8){
        const int e0 = 2302 - l0 + it*256 - 32*t - lr;
        const int e_idx = e0 < 0 ? 0 : (e0 > 2047 ? 2047 : e0);
        const float* Erow = E + (size_t)e_idx*64;
        f32x16 acc = zero16();
        #pragma unroll
        for (int tt=0;tt<4;tt++){
          f32x4 ea = *(const f32x4*)(Erow + tt*16 + hi*8);
          f32x4 eb = *(const f32x4*)(Erow + tt*16 + hi*8 + 4);
          u32x4 w;
          w[0]=pack2bf(ea[0],ea[1]); w[1]=pack2bf(ea[2],ea[3]);
          w[2]=pack2bf(eb[0],eb[1]); w[3]=pack2bf(eb[2],eb[3]);
          bf16x8 ef = __builtin_bit_cast(bf16x8, w);
          acc = __builtin_amdgcn_mfma_f32_32x32x16_bf16(ef, qf[tt], acc, 0,0,0);
        }
        #pragma unroll
        for (int g=0; g<16; g++)
          win[(t*32 + ROWPAT(g,hi))*32 + lr] = f2bf(acc[g]);
      }
      __syncthreads();
    }
    f32x16 acc = zero16();
    const unsigned short* Krow = Krows + (size_t)(s0 + lr)*64;
    #pragma unroll
    for (int t=0;t<4;t++){
      bf16x8 kf = *(const bf16x8*)(Krow + t*16 + hi*8);
      acc = __builtin_amdgcn_mfma_f32_32x32x16_bf16(kf, qf[t], acc, 0,0,0);
    }
    float p[16];
    #pragma unroll
    for (int g=0; g<16; g++){
      const int rp = ROWPAT(g,hi);
      const int s = s0 + rp;
      const int widx = lr + 255 - 32*wave - rp;
      const float rel = (s <= l) ? bf2f(win[widx*32 + lr]) : 0.f;
      p[g] = exp2f(((acc[g] + rel)*0.125f - m_run)*LOG2E) * inv_d;
    }
    // store attn_w row chunks: regs 4q..4q+3 are s = s0 + 8q + 4hi + {0..3}
    #pragma unroll
    for (int q=0;q<4;q++){
      f32x4 st;
      #pragma unroll
      for (int j=0;j<4;j++) st[j] = p[q*4+j];
      *(f32x4*)(awbase + s0 + q*8 + hi*4) = st;
    }
    // pack P to bf16 pairs; exchange halves so lane holds A-operand k-slices
    unsigned pk[8], sw[8];
    #pragma unroll
    for (int i=0;i<8;i++) pk[i] = pack2bf(p[i*2], p[i*2+1]);
    #pragma unroll
    for (int i=0;i<8;i++) sw[i] = (unsigned)__shfl_xor((int)pk[i], 32, 64);
    #pragma unroll
    for (int t=0;t<2;t++){
      u32x4 w;
      w[0] = hi ? sw[4*t+2] : pk[4*t];
      w[1] = hi ? sw[4*t+3] : pk[4*t+1];
      w[2] = hi ? pk[4*t+2] : sw[4*t];
      w[3] = hi ? pk[4*t+3] : sw[4*t+1];
      bf16x8 pa = __builtin_bit_cast(bf16x8, w);
      #pragma unroll
      for (int dt=0; dt<2; dt++){
        bf16x8 vfr = *(const bf16x8*)(Vtb + (size_t)(dt*32+lr)*2048 + s0 + t*16 + 8*hi);
        oacc[dt] = __builtin_amdgcn_mfma_f32_32x32x16_bf16(pa, vfr, oacc[dt], 0,0,0);
      }
    }
  }

  // ---- cross-wave reduce of PV partials: 4 deterministic 16KB rounds ----
  float* pvbuf = (float*)win;               // [8 waves][8 rows][64 cols]
  unsigned short* Obase = attn_o + ((size_t)bh*2048 + l0)*64;
  #pragma unroll 1
  for (int rd=0; rd<4; rd++){
    __syncthreads();
    #pragma unroll
    for (int gg=0; gg<4; gg++){
      const int g = rd*4 + gg;              // ROWPAT(g,hi) in [rd*8, rd*8+8)
      const int row = (g&3) + 4*hi;         // row within the 8-row slice
      #pragma unroll
      for (int dt=0; dt<2; dt++)
        pvbuf[wave*512 + row*64 + dt*32 + lr] = oacc[dt][g];
    }
    __syncthreads();
    const int row = tid >> 6, col = tid & 63;
    float s = 0.f;
    #pragma unroll
    for (int w=0; w<8; w++) s += pvbuf[w*512 + row*64 + col];
    Obase[(size_t)(rd*8 + row)*64 + col] = f2bf(s);
  }
}

// ---------------- K3: out(8192x512 fp32) = attn_gathered(bf16) @ fc_w + fc_b ----------------
__global__ __launch_bounds__(256,2) void fc_gemm_kernel(
    const unsigned short* __restrict__ A,   // [b,h,l,dh] bf16
    const unsigned int* __restrict__ Wt,    // fc_w^T [n][k] as uint pairs
    const float* __restrict__ bias, float* __restrict__ Out)
{
  __shared__ unsigned int Al[128][17];
  __shared__ unsigned int Bl[128][17];
  const int n0 = blockIdx.x * 128;
  const int m0 = blockIdx.y * 128;
  const int tid = threadIdx.x;
  const int lane = tid & 63, wave = tid >> 6;
  const int lr = lane & 31, hi = lane >> 5;
  const int wr = wave >> 1, wc = wave & 1;
  const int r = tid & 127, kh = tid >> 7;

  f32x16 acc[2][2];
  acc[0][0]=zero16(); acc[0][1]=zero16(); acc[1][0]=zero16(); acc[1][1]=zero16();

  for (int k0=0; k0<512; k0+=32){
    const int m = m0 + r; const int b = m >> 11, l = m & 2047;
    const int k = k0 + kh*16; const int h = k >> 6, dh0 = k & 63;
    const unsigned int* Ar = (const unsigned int*)(A + ((size_t)(b*8+h)*2048 + l)*64 + dh0);
    #pragma unroll
    for (int c=0;c<8;c++) Al[r][kh*8+c] = Ar[c];
    const unsigned int* Wr = Wt + (size_t)(n0 + r)*256 + (k0>>1) + kh*8;
    #pragma unroll
    for (int c=0;c<8;c++) Bl[r][kh*8 + c] = Wr[c];
    __syncthreads();
    #pragma unroll
    for (int t=0;t<2;t++){
      bf16x8 af[2], bfr[2];
      #pragma unroll
      for (int mt=0;mt<2;mt++){
        u32x4 w;
        #pragma unroll
        for (int j=0;j<4;j++) w[j] = Al[wr*64 + mt*32 + lr][t*8 + hi*4 + j];
        af[mt] = __builtin_bit_cast(bf16x8, w);
      }
      #pragma unroll
      for (int nt=0;nt<2;nt++){
        u32x4 w;
        #pragma unroll
        for (int j=0;j<4;j++) w[j] = Bl[wc*64 + nt*32 + lr][t*8 + hi*4 + j];
        bfr[nt] = __builtin_bit_cast(bf16x8, w);
      }
      #pragma unroll
      for (int mt=0;mt<2;mt++)
        #pragma unroll
        for (int nt=0;nt<2;nt++)
          acc[mt][nt] = __builtin_amdgcn_mfma_f32_32x32x16_bf16(af[mt], bfr[nt], acc[mt][nt], 0,0,0);
    }
    __syncthreads();
  }

  #pragma unroll
  for (int mt=0;mt<2;mt++)
    #pragma unroll
    for (int nt=0;nt<2;nt++){
      const int n = n0 + wc*64 + nt*32 + lr;
      const float bv = bias[n];
      #pragma unroll
      for (int g=0; g<16; g++){
        const int m2 = m0 + wr*64 + mt*32 + ROWPAT(g,hi);
        Out[(size_t)m2*512 + n] = acc[mt][nt][g] + bv;
      }
    }
}

extern "C" void kernel_launch(void* const* d_in, const int* in_sizes, int n_in,
                              void* d_out, int out_size, void* d_ws, size_t ws_size,
                              hipStream_t stream)
{
  const float* q_in = (const float*)d_in[0];
  const float* k_in = (const float*)d_in[1];
  const float* v_in = (const float*)d_in[2];
  const float* Wq_w = (const float*)d_in[3];
  const float* Wq_b = (const float*)d_in[4];
  const float* Wk_w = (const float*)d_in[5];
  const float* Wk_b = (const float*)d_in[6];
  const float* Wv_w = (const float*)d_in[7];
  const float* Wv_b = (const float*)d_in[8];
  const float* E    = (const float*)d_in[9];
  const float* fc_w = (const float*)d_in[10];
  const float* fc_b = (const float*)d_in[11];

  float* out = (float*)d_out;
  float* attn_w = out + (size_t)4*2048*512;

  unsigned short* Qws = (unsigned short*)d_ws;          // B*H*L*DH = 4194304 elems each
  unsigned short* Kws = Qws + (size_t)4194304;
  unsigned short* Vws = Kws + (size_t)4194304;
  unsigned short* ATT = Vws + (size_t)4194304;
  unsigned short* VTs = ATT + (size_t)4194304;
  unsigned short* WqT = VTs + (size_t)4194304;
  unsigned short* WkT = WqT + 262144;
  unsigned short* WvT = WkT + 262144;
  unsigned short* WfT = WvT + 262144;

  dim3 tg(16,16);
  hipLaunchKernelGGL(transpose_w_kernel, tg, dim3(256), 0, stream, Wq_w, WqT);
  hipLaunchKernelGGL(transpose_w_kernel, tg, dim3(256), 0, stream, Wk_w, WkT);
  hipLaunchKernelGGL(transpose_w_kernel, tg, dim3(256), 0, stream, Wv_w, WvT);
  hipLaunchKernelGGL(transpose_w_kernel, tg, dim3(256), 0, stream, fc_w, WfT);

  dim3 pg(4, 64);
  hipLaunchKernelGGL(proj_gemm_kernel, pg, dim3(256), 0, stream, q_in, (const unsigned int*)WqT, Wq_b, Qws);
  hipLaunchKernelGGL(proj_gemm_kernel, pg, dim3(256), 0, stream, k_in, (const unsigned int*)WkT, Wk_b, Kws);
  hipLaunchKernelGGL(proj_gemm_kernel, pg, dim3(256), 0, stream, v_in, (const unsigned int*)WvT, Wv_b, Vws);

  hipLaunchKernelGGL(transpose_v_kernel, dim3(64,2,32), dim3(256), 0, stream, Vws, VTs);

  hipLaunchKernelGGL(attn_kernel, dim3(64,32), dim3(512), 0, stream, Qws, Kws, VTs, E, attn_w, ATT);

  hipLaunchKernelGGL(fc_gemm_kernel, pg, dim3(256), 0, stream, ATT, (const unsigned int*)WfT, fc_b, out);
}

// Round 5
// 631.615 us; speedup vs baseline: 1.0568x; 1.0568x over previous
//
#include <hip/hip_runtime.h>

#define LOG2E 1.4426950408889634f
#define SC2   0.18033688011112042f   // 0.125 * log2(e)

typedef __attribute__((ext_vector_type(8)))  __bf16       bf16x8;
typedef __attribute__((ext_vector_type(16))) float        f32x16;
typedef __attribute__((ext_vector_type(4)))  float        f32x4;
typedef __attribute__((ext_vector_type(4)))  unsigned int u32x4;
typedef __attribute__((ext_vector_type(2)))  unsigned int u32x2;

#define ROWPAT(g, hi) ((((g)&3)) + 8*((g)>>2) + 4*(hi))

__device__ inline unsigned short f2bf(float f){
  unsigned u = __builtin_bit_cast(unsigned, f);
  u += 0x7FFFu + ((u >> 16) & 1u);
  return (unsigned short)(u >> 16);
}
__device__ inline float bf2f(unsigned short h){
  unsigned u = ((unsigned)h) << 16;
  return __builtin_bit_cast(float, u);
}
__device__ inline unsigned pack2bf(float lo, float hi){
  return (unsigned)f2bf(lo) | ((unsigned)f2bf(hi) << 16);
}
__device__ inline f32x16 zero16(){
  f32x16 z;
  #pragma unroll
  for (int i=0;i<16;i++) z[i]=0.f;
  return z;
}

// ---------------- K0: W (512x512 fp32, [k][n]) -> Wt bf16 [n][k] ----------------
__global__ __launch_bounds__(256) void transpose_w_kernel(const float* __restrict__ W,
                                                          unsigned short* __restrict__ Wt){
  __shared__ unsigned short t[32][33];
  const int n0 = blockIdx.x*32, k0 = blockIdx.y*32;
  const int tx = threadIdx.x & 31, ty = threadIdx.x >> 5;   // ty 0..7
  #pragma unroll
  for (int i=0;i<4;i++){
    int k = ty*4 + i;
    t[k][tx] = f2bf(W[(size_t)(k0+k)*512 + n0+tx]);
  }
  __syncthreads();
  #pragma unroll
  for (int i=0;i<4;i++){
    int n = ty*4+i;
    Wt[(size_t)(n0+n)*512 + k0 + tx] = t[tx][n];
  }
}

// ---------------- K0b: V [bh][l][dh] bf16 -> VT [bh][dh][l] bf16 ----------------
__global__ __launch_bounds__(256) void transpose_v_kernel(const unsigned short* __restrict__ V,
                                                          unsigned short* __restrict__ VT){
  __shared__ unsigned short t[32][33];
  const int bh = blockIdx.z;
  const int l0 = blockIdx.x*32, d0 = blockIdx.y*32;
  const int tx = threadIdx.x & 31, ty = threadIdx.x >> 5;
  const unsigned short* Vb = V + (size_t)bh*2048*64;
  unsigned short* Tb = VT + (size_t)bh*64*2048;
  #pragma unroll
  for (int i=0;i<4;i++){
    int row = ty*4+i;
    t[row][tx] = Vb[(size_t)(l0+row)*64 + d0+tx];
  }
  __syncthreads();
  #pragma unroll
  for (int i=0;i<4;i++){
    int d = ty*4+i;
    Tb[(size_t)(d0+d)*2048 + l0+tx] = t[tx][d];
  }
}

// ---------------- K1: Y[b,h,l,dh] (bf16) = X(8192x512 fp32) @ W + bias ----------------
__global__ __launch_bounds__(256,2) void proj_gemm_kernel(
    const float* __restrict__ X, const unsigned int* __restrict__ Wt,
    const float* __restrict__ bias, unsigned short* __restrict__ Y)
{
  __shared__ unsigned int Al[128][17];
  __shared__ unsigned int Bl[128][17];
  const int n0 = blockIdx.x * 128;
  const int m0 = blockIdx.y * 128;
  const int tid = threadIdx.x;
  const int lane = tid & 63, wave = tid >> 6;
  const int lr = lane & 31, hi = lane >> 5;
  const int wr = wave >> 1, wc = wave & 1;
  const int r = tid & 127, kh = tid >> 7;

  f32x16 acc[2][2];
  acc[0][0]=zero16(); acc[0][1]=zero16(); acc[1][0]=zero16(); acc[1][1]=zero16();

  for (int k0=0; k0<512; k0+=32){
    const float* Xr = X + (size_t)(m0 + r)*512 + k0 + kh*16;
    #pragma unroll
    for (int c=0;c<2;c++){
      f32x4 x0 = *(const f32x4*)(Xr + c*8);
      f32x4 x1 = *(const f32x4*)(Xr + c*8 + 4);
      Al[r][kh*8 + c*4 + 0] = pack2bf(x0[0], x0[1]);
      Al[r][kh*8 + c*4 + 1] = pack2bf(x0[2], x0[3]);
      Al[r][kh*8 + c*4 + 2] = pack2bf(x1[0], x1[1]);
      Al[r][kh*8 + c*4 + 3] = pack2bf(x1[2], x1[3]);
    }
    const unsigned int* Wr = Wt + (size_t)(n0 + r)*256 + (k0>>1) + kh*8;
    #pragma unroll
    for (int c=0;c<8;c++) Bl[r][kh*8 + c] = Wr[c];
    __syncthreads();
    #pragma unroll
    for (int t=0;t<2;t++){
      bf16x8 af[2], bfr[2];
      #pragma unroll
      for (int mt=0;mt<2;mt++){
        u32x4 w;
        #pragma unroll
        for (int j=0;j<4;j++) w[j] = Al[wr*64 + mt*32 + lr][t*8 + hi*4 + j];
        af[mt] = __builtin_bit_cast(bf16x8, w);
      }
      #pragma unroll
      for (int nt=0;nt<2;nt++){
        u32x4 w;
        #pragma unroll
        for (int j=0;j<4;j++) w[j] = Bl[wc*64 + nt*32 + lr][t*8 + hi*4 + j];
        bfr[nt] = __builtin_bit_cast(bf16x8, w);
      }
      #pragma unroll
      for (int mt=0;mt<2;mt++)
        #pragma unroll
        for (int nt=0;nt<2;nt++)
          acc[mt][nt] = __builtin_amdgcn_mfma_f32_32x32x16_bf16(af[mt], bfr[nt], acc[mt][nt], 0,0,0);
    }
    __syncthreads();
  }

  #pragma unroll
  for (int mt=0;mt<2;mt++)
    #pragma unroll
    for (int nt=0;nt<2;nt++){
      const int n = n0 + wc*64 + nt*32 + lr;
      const float bv = bias[n];
      const int h = n >> 6, dh = n & 63;
      #pragma unroll
      for (int g=0; g<16; g++){
        const int m = m0 + wr*64 + mt*32 + ROWPAT(g,hi);
        const int b = m >> 11, l = m & 2047;
        Y[((size_t)(b*8 + h)*2048 + l)*64 + dh] = f2bf(acc[mt][nt][g] + bv);
      }
    }
}

// ---------------- K2: fused relative attention — single K-pass, fixed max=0 ----------------
// Non-swapped orientation: C row = l (regs), col = s (lanes).
// Phase 1: QK + windowed Srel + exp -> pk (bf16, unnormalized) in 64 VGPRs, d-partials.
// Merge: butterfly over lanes + LDS over waves -> inv_d per row (reg-indexed).
// Phase 2: coalesced scaled attn_w stores + PV via wave-local LDS transpose.
#define WSTR 290
__global__ __launch_bounds__(512,2) void attn_kernel(
    const unsigned short* __restrict__ Q,
    const unsigned short* __restrict__ Kb,
    const unsigned short* __restrict__ VT,
    const float* __restrict__ E,
    float* __restrict__ attn_w,
    unsigned short* __restrict__ attn_o)
{
  __shared__ unsigned short win[32*WSTR];   // 18.6 KB; aliased: P-slabs (18.4 KB), pv-reduce (16 KB)
  __shared__ float mdt[8][32];
  __shared__ float dtot[32];
  const int l0 = blockIdx.x * 32;
  const int bh = blockIdx.y;
  const int tid = threadIdx.x;
  const int wave = tid >> 6;
  const int lane = tid & 63;
  const int lr = lane & 31;
  const int hi = lane >> 5;
  const int s0w = wave*32;

  // Q fragments, A-operand: lane holds row l = l0+lr, k-slice d = 16t + 8hi + j
  const unsigned short* Qrow = Q + ((size_t)bh*2048 + l0 + lr)*64;
  bf16x8 qf[4];
  #pragma unroll
  for (int t=0;t<4;t++) qf[t] = *(const bf16x8*)(Qrow + t*16 + hi*8);

  const unsigned short* Krows = Kb + (size_t)bh*2048*64;

  float dpart[16];
  #pragma unroll
  for (int g=0;g<16;g++) dpart[g] = 0.f;
  unsigned pk[8][8];

  // ---- phase 1: single pass over s ----
  #pragma unroll
  for (int it=0; it<8; ++it){
    const int thr = 255 + it*256 - l0;     // mask: rel valid iff u_local >= thr
    if (thr <= 286){
      __syncthreads();                     // prior window fully consumed
      #pragma unroll 1
      for (int t = wave; t < 9; t += 8){   // build win[l][u_local], u_local = 32t + rowpat
        const int e0 = 2302 - l0 + it*256 - 32*t - lr;   // E row = 2047 - u
        const int e_idx = e0 < 0 ? 0 : (e0 > 2047 ? 2047 : e0);
        const float* Erow = E + (size_t)e_idx*64;
        f32x16 acc = zero16();
        #pragma unroll
        for (int tt=0;tt<4;tt++){
          f32x4 ea = *(const f32x4*)(Erow + tt*16 + hi*8);
          f32x4 eb = *(const f32x4*)(Erow + tt*16 + hi*8 + 4);
          u32x4 w;
          w[0]=pack2bf(ea[0],ea[1]); w[1]=pack2bf(ea[2],ea[3]);
          w[2]=pack2bf(eb[0],eb[1]); w[3]=pack2bf(eb[2],eb[3]);
          bf16x8 ef = __builtin_bit_cast(bf16x8, w);
          acc = __builtin_amdgcn_mfma_f32_32x32x16_bf16(ef, qf[tt], acc, 0,0,0);
        }
        #pragma unroll
        for (int g=0; g<16; g++)
          win[lr*WSTR + 32*t + ROWPAT(g,hi)] = f2bf(acc[g]);
      }
      __syncthreads();                     // window ready
    }
    const int s0 = it*256 + s0w;
    f32x16 acc = zero16();
    const unsigned short* Krow = Krows + (size_t)(s0 + lr)*64;   // B-operand: lane = col s
    #pragma unroll
    for (int t=0;t<4;t++){
      bf16x8 kf = *(const bf16x8*)(Krow + t*16 + hi*8);
      acc = __builtin_amdgcn_mfma_f32_32x32x16_bf16(qf[t], kf, acc, 0,0,0);
    }
    float p[16];
    #pragma unroll
    for (int g=0; g<16; g++){
      const int rp = ROWPAT(g,hi);
      const int ul = rp - lr + 255 - s0w;          // u_local in [0,286]
      const float rel = (ul >= thr) ? bf2f(win[rp*WSTR + ul]) : 0.f;
      p[g] = exp2f((acc[g] + rel) * SC2);          // unnormalized, m=0
      dpart[g] += p[g];
    }
    #pragma unroll
    for (int q=0;q<8;q++) pk[it][q] = pack2bf(p[2*q], p[2*q+1]);
  }

  // ---- d merge: butterfly over 32 lanes (s), then across waves via LDS ----
  #pragma unroll
  for (int g=0; g<16; g++){
    float v = dpart[g];
    v += __shfl_xor(v, 1, 64);
    v += __shfl_xor(v, 2, 64);
    v += __shfl_xor(v, 4, 64);
    v += __shfl_xor(v, 8, 64);
    v += __shfl_xor(v, 16, 64);
    dpart[g] = v;
  }
  __syncthreads();                         // win reads done; safe to alias later
  if (lr == 0){
    #pragma unroll
    for (int g=0; g<16; g++) mdt[wave][ROWPAT(g,hi)] = dpart[g];
  }
  __syncthreads();
  if (tid < 32){
    float s = 0.f;
    #pragma unroll
    for (int w=0; w<8; w++) s += mdt[w][tid];
    dtot[tid] = s;
  }
  __syncthreads();
  float invd[16];
  #pragma unroll
  for (int g=0; g<16; g++) invd[g] = 1.0f / dtot[ROWPAT(g,hi)];

  // ---- phase 2: scaled attn_w stores + PV (wave-local, no barriers) ----
  unsigned short* Ps = win + wave*(32*36);            // per-wave P slab [32 l][36 s-pad] u16
  const unsigned short* Vtb = VT + (size_t)bh*64*2048;
  f32x16 oacc[2];
  oacc[0]=zero16(); oacc[1]=zero16();

  #pragma unroll
  for (int it=0; it<8; ++it){
    const int s0 = it*256 + s0w;
    // stage P tile into LDS (row l, col s-local)
    #pragma unroll
    for (int q=0;q<8;q++){
      const int rp0 = ROWPAT(2*q,hi);
      Ps[rp0*36 + lr]     = (unsigned short)(pk[it][q] & 0xFFFFu);
      Ps[(rp0+1)*36 + lr] = (unsigned short)(pk[it][q] >> 16);
    }
    // coalesced attn_w stores: per g, 2 rows x 32 consecutive s (2 full 128B lines)
    #pragma unroll
    for (int g=0; g<16; g++){
      const int rp = ROWPAT(g,hi);
      const float v = bf2f((unsigned short)((pk[it][g>>1] >> ((g&1)*16)) & 0xFFFFu)) * invd[g];
      __builtin_nontemporal_store(v, attn_w + ((size_t)bh*2048 + l0 + rp)*2048 + s0 + lr);
    }
    // A-frags from LDS transpose: lane = row l, k-slice = s-local
    bf16x8 af[2];
    #pragma unroll
    for (int sh=0; sh<2; sh++){
      const unsigned short* ap = Ps + lr*36 + sh*16 + 8*hi;
      u32x2 a0 = *(const u32x2*)(ap);
      u32x2 a1 = *(const u32x2*)(ap + 4);
      u32x4 w; w[0]=a0[0]; w[1]=a0[1]; w[2]=a1[0]; w[3]=a1[1];
      af[sh] = __builtin_bit_cast(bf16x8, w);
    }
    #pragma unroll
    for (int sh=0; sh<2; sh++){
      #pragma unroll
      for (int dt=0; dt<2; dt++){
        bf16x8 vfr = *(const bf16x8*)(Vtb + (size_t)(dt*32+lr)*2048 + s0 + sh*16 + 8*hi);
        oacc[dt] = __builtin_amdgcn_mfma_f32_32x32x16_bf16(af[sh], vfr, oacc[dt], 0,0,0);
      }
    }
  }
  // scale PV partials by inv_d (rows are reg-indexed, same map as invd)
  #pragma unroll
  for (int dt=0; dt<2; dt++)
    #pragma unroll
    for (int g=0; g<16; g++) oacc[dt][g] *= invd[g];

  // ---- cross-wave reduce of PV partials: 4 rounds of 16KB ----
  float* pvbuf = (float*)win;               // [8 waves][8 rows][64 cols]
  unsigned short* Obase = attn_o + ((size_t)bh*2048 + l0)*64;
  #pragma unroll 1
  for (int rd=0; rd<4; rd++){
    __syncthreads();
    #pragma unroll
    for (int gg=0; gg<4; gg++){
      const int g = rd*4 + gg;              // ROWPAT(g,hi) in [rd*8, rd*8+8)
      const int row = (g&3) + 4*hi;
      #pragma unroll
      for (int dt=0; dt<2; dt++)
        pvbuf[wave*512 + row*64 + dt*32 + lr] = oacc[dt][g];
    }
    __syncthreads();
    const int row = tid >> 6, col = tid & 63;
    float s = 0.f;
    #pragma unroll
    for (int w=0; w<8; w++) s += pvbuf[w*512 + row*64 + col];
    Obase[(size_t)(rd*8 + row)*64 + col] = f2bf(s);
  }
}

// ---------------- K3: out(8192x512 fp32) = attn_gathered(bf16) @ fc_w + fc_b ----------------
__global__ __launch_bounds__(256,2) void fc_gemm_kernel(
    const unsigned short* __restrict__ A,   // [b,h,l,dh] bf16
    const unsigned int* __restrict__ Wt,    // fc_w^T [n][k] as uint pairs
    const float* __restrict__ bias, float* __restrict__ Out)
{
  __shared__ unsigned int Al[128][17];
  __shared__ unsigned int Bl[128][17];
  const int n0 = blockIdx.x * 128;
  const int m0 = blockIdx.y * 128;
  const int tid = threadIdx.x;
  const int lane = tid & 63, wave = tid >> 6;
  const int lr = lane & 31, hi = lane >> 5;
  const int wr = wave >> 1, wc = wave & 1;
  const int r = tid & 127, kh = tid >> 7;

  f32x16 acc[2][2];
  acc[0][0]=zero16(); acc[0][1]=zero16(); acc[1][0]=zero16(); acc[1][1]=zero16();

  for (int k0=0; k0<512; k0+=32){
    const int m = m0 + r; const int b = m >> 11, l = m & 2047;
    const int k = k0 + kh*16; const int h = k >> 6, dh0 = k & 63;
    const unsigned int* Ar = (const unsigned int*)(A + ((size_t)(b*8+h)*2048 + l)*64 + dh0);
    #pragma unroll
    for (int c=0;c<8;c++) Al[r][kh*8+c] = Ar[c];
    const unsigned int* Wr = Wt + (size_t)(n0 + r)*256 + (k0>>1) + kh*8;
    #pragma unroll
    for (int c=0;c<8;c++) Bl[r][kh*8 + c] = Wr[c];
    __syncthreads();
    #pragma unroll
    for (int t=0;t<2;t++){
      bf16x8 af[2], bfr[2];
      #pragma unroll
      for (int mt=0;mt<2;mt++){
        u32x4 w;
        #pragma unroll
        for (int j=0;j<4;j++) w[j] = Al[wr*64 + mt*32 + lr][t*8 + hi*4 + j];
        af[mt] = __builtin_bit_cast(bf16x8, w);
      }
      #pragma unroll
      for (int nt=0;nt<2;nt++){
        u32x4 w;
        #pragma unroll
        for (int j=0;j<4;j++) w[j] = Bl[wc*64 + nt*32 + lr][t*8 + hi*4 + j];
        bfr[nt] = __builtin_bit_cast(bf16x8, w);
      }
      #pragma unroll
      for (int mt=0;mt<2;mt++)
        #pragma unroll
        for (int nt=0;nt<2;nt++)
          acc[mt][nt] = __builtin_amdgcn_mfma_f32_32x32x16_bf16(af[mt], bfr[nt], acc[mt][nt], 0,0,0);
    }
    __syncthreads();
  }

  #pragma unroll
  for (int mt=0;mt<2;mt++)
    #pragma unroll
    for (int nt=0;nt<2;nt++){
      const int n = n0 + wc*64 + nt*32 + lr;
      const float bv = bias[n];
      #pragma unroll
      for (int g=0; g<16; g++){
        const int m2 = m0 + wr*64 + mt*32 + ROWPAT(g,hi);
        Out[(size_t)m2*512 + n] = acc[mt][nt][g] + bv;
      }
    }
}

extern "C" void kernel_launch(void* const* d_in, const int* in_sizes, int n_in,
                              void* d_out, int out_size, void* d_ws, size_t ws_size,
                              hipStream_t stream)
{
  const float* q_in = (const float*)d_in[0];
  const float* k_in = (const float*)d_in[1];
  const float* v_in = (const float*)d_in[2];
  const float* Wq_w = (const float*)d_in[3];
  const float* Wq_b = (const float*)d_in[4];
  const float* Wk_w = (const float*)d_in[5];
  const float* Wk_b = (const float*)d_in[6];
  const float* Wv_w = (const float*)d_in[7];
  const float* Wv_b = (const float*)d_in[8];
  const float* E    = (const float*)d_in[9];
  const float* fc_w = (const float*)d_in[10];
  const float* fc_b = (const float*)d_in[11];

  float* out = (float*)d_out;
  float* attn_w = out + (size_t)4*2048*512;

  unsigned short* Qws = (unsigned short*)d_ws;          // B*H*L*DH = 4194304 elems each
  unsigned short* Kws = Qws + (size_t)4194304;
  unsigned short* Vws = Kws + (size_t)4194304;
  unsigned short* ATT = Vws + (size_t)4194304;
  unsigned short* VTs = ATT + (size_t)4194304;
  unsigned short* WqT = VTs + (size_t)4194304;
  unsigned short* WkT = WqT + 262144;
  unsigned short* WvT = WkT + 262144;
  unsigned short* WfT = WvT + 262144;

  dim3 tg(16,16);
  hipLaunchKernelGGL(transpose_w_kernel, tg, dim3(256), 0, stream, Wq_w, WqT);
  hipLaunchKernelGGL(transpose_w_kernel, tg, dim3(256), 0, stream, Wk_w, WkT);
  hipLaunchKernelGGL(transpose_w_kernel, tg, dim3(256), 0, stream, Wv_w, WvT);
  hipLaunchKernelGGL(transpose_w_kernel, tg, dim3(256), 0, stream, fc_w, WfT);

  dim3 pg(4, 64);
  hipLaunchKernelGGL(proj_gemm_kernel, pg, dim3(256), 0, stream, q_in, (const unsigned int*)WqT, Wq_b, Qws);
  hipLaunchKernelGGL(proj_gemm_kernel, pg, dim3(256), 0, stream, k_in, (const unsigned int*)WkT, Wk_b, Kws);
  hipLaunchKernelGGL(proj_gemm_kernel, pg, dim3(256), 0, stream, v_in, (const unsigned int*)WvT, Wv_b, Vws);

  hipLaunchKernelGGL(transpose_v_kernel, dim3(64,2,32), dim3(256), 0, stream, Vws, VTs);

  hipLaunchKernelGGL(attn_kernel, dim3(64,32), dim3(512), 0, stream, Qws, Kws, VTs, E, attn_w, ATT);

  hipLaunchKernelGGL(fc_gemm_kernel, pg, dim3(256), 0, stream, ATT, (const unsigned int*)WfT, fc_b, out);
}

// Round 6
// 522.866 us; speedup vs baseline: 1.2766x; 1.2080x over previous
//
#include <hip/hip_runtime.h>

#define SC2   0.18033688011112042f   // 0.125 * log2(e)
#define PSTR  36

typedef __attribute__((ext_vector_type(8)))  __bf16       bf16x8;
typedef __attribute__((ext_vector_type(16))) float        f32x16;
typedef __attribute__((ext_vector_type(4)))  float        f32x4;
typedef __attribute__((ext_vector_type(4)))  unsigned int u32x4;
typedef __attribute__((ext_vector_type(2)))  unsigned int u32x2;

#define ROWPAT(g, hi) ((((g)&3)) + 8*((g)>>2) + 4*(hi))

__device__ inline unsigned short f2bf(float f){
  unsigned u = __builtin_bit_cast(unsigned, f);
  u += 0x7FFFu + ((u >> 16) & 1u);
  return (unsigned short)(u >> 16);
}
__device__ inline float bf2f(unsigned short h){
  unsigned u = ((unsigned)h) << 16;
  return __builtin_bit_cast(float, u);
}
__device__ inline unsigned pack2bf(float lo, float hi){
  return (unsigned)f2bf(lo) | ((unsigned)f2bf(hi) << 16);
}
__device__ inline f32x16 zero16(){
  f32x16 z;
  #pragma unroll
  for (int i=0;i<16;i++) z[i]=0.f;
  return z;
}

// ---------------- K0: W (512x512 fp32, [k][n]) -> Wt bf16 [n][k] ----------------
__global__ __launch_bounds__(256) void transpose_w_kernel(const float* __restrict__ W,
                                                          unsigned short* __restrict__ Wt){
  __shared__ unsigned short t[32][33];
  const int n0 = blockIdx.x*32, k0 = blockIdx.y*32;
  const int tx = threadIdx.x & 31, ty = threadIdx.x >> 5;
  #pragma unroll
  for (int i=0;i<4;i++){
    int k = ty*4 + i;
    t[k][tx] = f2bf(W[(size_t)(k0+k)*512 + n0+tx]);
  }
  __syncthreads();
  #pragma unroll
  for (int i=0;i<4;i++){
    int n = ty*4+i;
    Wt[(size_t)(n0+n)*512 + k0 + tx] = t[tx][n];
  }
}

// ---------------- K0b: V [bh][l][dh] bf16 -> VT [bh][dh][l] bf16 ----------------
__global__ __launch_bounds__(256) void transpose_v_kernel(const unsigned short* __restrict__ V,
                                                          unsigned short* __restrict__ VT){
  __shared__ unsigned short t[32][33];
  const int bh = blockIdx.z;
  const int l0 = blockIdx.x*32, d0 = blockIdx.y*32;
  const int tx = threadIdx.x & 31, ty = threadIdx.x >> 5;
  const unsigned short* Vb = V + (size_t)bh*2048*64;
  unsigned short* Tb = VT + (size_t)bh*64*2048;
  #pragma unroll
  for (int i=0;i<4;i++){
    int row = ty*4+i;
    t[row][tx] = Vb[(size_t)(l0+row)*64 + d0+tx];
  }
  __syncthreads();
  #pragma unroll
  for (int i=0;i<4;i++){
    int d = ty*4+i;
    Tb[(size_t)(d0+d)*2048 + l0+tx] = t[tx][d];
  }
}

// ---------------- K0c: Ebf[u][d] = bf16(E[2047-u][d]) ----------------
__global__ __launch_bounds__(256) void erev_kernel(const float* __restrict__ E,
                                                   unsigned short* __restrict__ Ebf){
  const int i = blockIdx.x*256 + threadIdx.x;      // one thread per 4 elems; 32768 threads
  const int base = i*4;
  const int u = base >> 6, d = base & 63;
  f32x4 v = *(const f32x4*)(E + (size_t)(2047 - u)*64 + d);
  unsigned short o[4];
  #pragma unroll
  for (int j=0;j<4;j++) o[j] = f2bf(v[j]);
  *(u32x2*)(Ebf + (size_t)u*64 + d) = u32x2{(unsigned)o[0] | ((unsigned)o[1]<<16),
                                            (unsigned)o[2] | ((unsigned)o[3]<<16)};
}

// ---------------- K1: Y[b,h,l,dh] (bf16) = X(8192x512 fp32) @ W + bias ----------------
__global__ __launch_bounds__(256,2) void proj_gemm_kernel(
    const float* __restrict__ X, const unsigned int* __restrict__ Wt,
    const float* __restrict__ bias, unsigned short* __restrict__ Y)
{
  __shared__ unsigned int Al[128][17];
  __shared__ unsigned int Bl[128][17];
  const int n0 = blockIdx.x * 128;
  const int m0 = blockIdx.y * 128;
  const int tid = threadIdx.x;
  const int lane = tid & 63, wave = tid >> 6;
  const int lr = lane & 31, hi = lane >> 5;
  const int wr = wave >> 1, wc = wave & 1;
  const int r = tid & 127, kh = tid >> 7;

  f32x16 acc[2][2];
  acc[0][0]=zero16(); acc[0][1]=zero16(); acc[1][0]=zero16(); acc[1][1]=zero16();

  for (int k0=0; k0<512; k0+=32){
    const float* Xr = X + (size_t)(m0 + r)*512 + k0 + kh*16;
    #pragma unroll
    for (int c=0;c<2;c++){
      f32x4 x0 = *(const f32x4*)(Xr + c*8);
      f32x4 x1 = *(const f32x4*)(Xr + c*8 + 4);
      Al[r][kh*8 + c*4 + 0] = pack2bf(x0[0], x0[1]);
      Al[r][kh*8 + c*4 + 1] = pack2bf(x0[2], x0[3]);
      Al[r][kh*8 + c*4 + 2] = pack2bf(x1[0], x1[1]);
      Al[r][kh*8 + c*4 + 3] = pack2bf(x1[2], x1[3]);
    }
    const unsigned int* Wr = Wt + (size_t)(n0 + r)*256 + (k0>>1) + kh*8;
    #pragma unroll
    for (int c=0;c<8;c++) Bl[r][kh*8 + c] = Wr[c];
    __syncthreads();
    #pragma unroll
    for (int t=0;t<2;t++){
      bf16x8 af[2], bfr[2];
      #pragma unroll
      for (int mt=0;mt<2;mt++){
        u32x4 w;
        #pragma unroll
        for (int j=0;j<4;j++) w[j] = Al[wr*64 + mt*32 + lr][t*8 + hi*4 + j];
        af[mt] = __builtin_bit_cast(bf16x8, w);
      }
      #pragma unroll
      for (int nt=0;nt<2;nt++){
        u32x4 w;
        #pragma unroll
        for (int j=0;j<4;j++) w[j] = Bl[wc*64 + nt*32 + lr][t*8 + hi*4 + j];
        bfr[nt] = __builtin_bit_cast(bf16x8, w);
      }
      #pragma unroll
      for (int mt=0;mt<2;mt++)
        #pragma unroll
        for (int nt=0;nt<2;nt++)
          acc[mt][nt] = __builtin_amdgcn_mfma_f32_32x32x16_bf16(af[mt], bfr[nt], acc[mt][nt], 0,0,0);
    }
    __syncthreads();
  }

  #pragma unroll
  for (int mt=0;mt<2;mt++)
    #pragma unroll
    for (int nt=0;nt<2;nt++){
      const int n = n0 + wc*64 + nt*32 + lr;
      const float bv = bias[n];
      const int h = n >> 6, dh = n & 63;
      #pragma unroll
      for (int g=0; g<16; g++){
        const int m = m0 + wr*64 + mt*32 + ROWPAT(g,hi);
        const int b = m >> 11, l = m & 2047;
        Y[((size_t)(b*8 + h)*2048 + l)*64 + dh] = f2bf(acc[mt][nt][g] + bv);
      }
    }
}

// ---------------- K2: fused relative attention — wave-autonomous, ZERO barriers ----------------
// 256 threads (4 waves); each wave owns 32 q-rows (l0w = (bid.x + 16*wave)*32) and the
// FULL s range. Pass 1: QK+rel -> d (wave-local butterfly). Pass 2: recompute, write
// attn_w (normalized), PV accumulate. Srel via wave-private 2-slab window cache:
// descending rel-chunks, 1 new QE subtile per chunk.
__global__ __launch_bounds__(256) void attn_kernel(
    const unsigned short* __restrict__ Q,
    const unsigned short* __restrict__ Kb,
    const unsigned short* __restrict__ VT,
    const unsigned short* __restrict__ Ebf,
    float* __restrict__ attn_w,
    unsigned short* __restrict__ attn_o)
{
  __shared__ unsigned short slab[4][3*32*PSTR];   // per wave: Wa, Wb, Ps  (27.6 KB total)
  const int bh = blockIdx.y;
  const int tid = threadIdx.x;
  const int wave = tid >> 6;
  const int lane = tid & 63;
  const int lr = lane & 31;
  const int hi = lane >> 5;
  const int l0w = (blockIdx.x + 16*wave)*32;
  const int c_max = blockIdx.x + 16*wave;         // chunks 0..c_max have rel terms

  unsigned short* Wa = &slab[wave][0];
  unsigned short* Wb = Wa + 32*PSTR;
  unsigned short* Ps = Wb + 32*PSTR;

  // Q fragments (A-operand: lane row = l-local lr, k-slice d)
  const unsigned short* Qrow = Q + ((size_t)bh*2048 + l0w + lr)*64;
  bf16x8 qf[4];
  #pragma unroll
  for (int t=0;t<4;t++) qf[t] = *(const bf16x8*)(Qrow + t*16 + hi*8);

  const unsigned short* Krows = Kb + (size_t)bh*2048*64;
  const unsigned short* Vtb   = VT + (size_t)bh*64*2048;

  float dpart[16];
  #pragma unroll
  for (int g=0;g<16;g++) dpart[g] = 0.f;

  // ================= PASS 1: denominator =================
  #pragma unroll 2
  for (int c = c_max+1; c < 64; ++c){             // no-rel chunks
    const int s0 = c*32;
    f32x16 acc = zero16();
    const unsigned short* Krow = Krows + (size_t)(s0 + lr)*64;
    #pragma unroll
    for (int t=0;t<4;t++){
      bf16x8 kf = *(const bf16x8*)(Krow + t*16 + hi*8);
      acc = __builtin_amdgcn_mfma_f32_32x32x16_bf16(qf[t], kf, acc, 0,0,0);
    }
    #pragma unroll
    for (int g=0; g<16; g++) dpart[g] += exp2f(acc[g] * SC2);
  }
  {
    unsigned short* cur = Wa;
    unsigned short* prv = Wb;
    #pragma unroll 1
    for (int c = c_max; c >= 0; --c){             // rel chunks, descending (delta grows)
      const int s0 = c*32;
      const int delta = l0w - s0;
      // build QE subtile: u = delta + lr  (col), rows l on regs
      {
        const unsigned short* Erow = Ebf + (size_t)(delta + lr)*64;
        f32x16 eacc = zero16();
        #pragma unroll
        for (int t=0;t<4;t++){
          bf16x8 ef = *(const bf16x8*)(Erow + t*16 + hi*8);
          eacc = __builtin_amdgcn_mfma_f32_32x32x16_bf16(qf[t], ef, eacc, 0,0,0);
        }
        #pragma unroll
        for (int g=0; g<16; g++) cur[ROWPAT(g,hi)*PSTR + lr] = f2bf(eacc[g]);
      }
      f32x16 acc = zero16();
      const unsigned short* Krow = Krows + (size_t)(s0 + lr)*64;
      #pragma unroll
      for (int t=0;t<4;t++){
        bf16x8 kf = *(const bf16x8*)(Krow + t*16 + hi*8);
        acc = __builtin_amdgcn_mfma_f32_32x32x16_bf16(qf[t], kf, acc, 0,0,0);
      }
      #pragma unroll
      for (int g=0; g<16; g++){
        const int rp = ROWPAT(g,hi);
        const int dloc = rp - lr;
        float v = acc[g];
        if (delta + dloc >= 0)
          v += bf2f(dloc >= 0 ? cur[rp*PSTR + dloc] : prv[rp*PSTR + 32 + dloc]);
        dpart[g] += exp2f(v * SC2);
      }
      unsigned short* tmp = cur; cur = prv; prv = tmp;
    }
  }
  // wave-local d reduce: butterfly over the 32 lanes holding this half's columns
  float invd[16];
  #pragma unroll
  for (int g=0; g<16; g++){
    float v = dpart[g];
    v += __shfl_xor(v, 1, 64);
    v += __shfl_xor(v, 2, 64);
    v += __shfl_xor(v, 4, 64);
    v += __shfl_xor(v, 8, 64);
    v += __shfl_xor(v, 16, 64);
    invd[g] = 1.0f / v;
  }

  // ================= PASS 2: attn_w + PV =================
  f32x16 oacc[2];
  oacc[0]=zero16(); oacc[1]=zero16();
  float* awbase = attn_w + ((size_t)bh*2048 + l0w)*2048;

  #pragma unroll 1
  for (int half=0; half<2; ++half){
    // half 0: rel chunks descending; half 1: no-rel chunks
    unsigned short* cur = Wa;
    unsigned short* prv = Wb;
    const int cbeg = half ? c_max+1 : c_max;
    const int cend = half ? 64 : -1;
    const int cstp = half ? 1 : -1;
    #pragma unroll 1
    for (int c = cbeg; c != cend; c += cstp){
      const int s0 = c*32;
      const int delta = l0w - s0;
      if (!half){
        const unsigned short* Erow = Ebf + (size_t)(delta + lr)*64;
        f32x16 eacc = zero16();
        #pragma unroll
        for (int t=0;t<4;t++){
          bf16x8 ef = *(const bf16x8*)(Erow + t*16 + hi*8);
          eacc = __builtin_amdgcn_mfma_f32_32x32x16_bf16(qf[t], ef, eacc, 0,0,0);
        }
        #pragma unroll
        for (int g=0; g<16; g++) cur[ROWPAT(g,hi)*PSTR + lr] = f2bf(eacc[g]);
      }
      f32x16 acc = zero16();
      const unsigned short* Krow = Krows + (size_t)(s0 + lr)*64;
      #pragma unroll
      for (int t=0;t<4;t++){
        bf16x8 kf = *(const bf16x8*)(Krow + t*16 + hi*8);
        acc = __builtin_amdgcn_mfma_f32_32x32x16_bf16(qf[t], kf, acc, 0,0,0);
      }
      float p[16];
      #pragma unroll
      for (int g=0; g<16; g++){
        const int rp = ROWPAT(g,hi);
        float v = acc[g];
        if (!half){
          const int dloc = rp - lr;
          if (delta + dloc >= 0)
            v += bf2f(dloc >= 0 ? cur[rp*PSTR + dloc] : prv[rp*PSTR + 32 + dloc]);
        }
        p[g] = exp2f(v * SC2) * invd[g];          // normalized
        __builtin_nontemporal_store(p[g], awbase + (size_t)rp*2048 + s0 + lr);
      }
      // stage P (normalized, bf16) for the PV transpose: Ps[l-local][s-local]
      #pragma unroll
      for (int q=0;q<8;q++){
        const int rp0 = ROWPAT(2*q,hi);
        const unsigned pkv = pack2bf(p[2*q], p[2*q+1]);
        Ps[rp0*PSTR + lr]     = (unsigned short)(pkv & 0xFFFFu);
        Ps[(rp0+1)*PSTR + lr] = (unsigned short)(pkv >> 16);
      }
      // PV: A = P[l][s] (lane row = lr), B = VT[dh][s]
      bf16x8 af[2];
      #pragma unroll
      for (int sh=0; sh<2; sh++){
        const unsigned short* ap = Ps + lr*PSTR + sh*16 + 8*hi;
        u32x2 a0 = *(const u32x2*)(ap);
        u32x2 a1 = *(const u32x2*)(ap + 4);
        u32x4 w; w[0]=a0[0]; w[1]=a0[1]; w[2]=a1[0]; w[3]=a1[1];
        af[sh] = __builtin_bit_cast(bf16x8, w);
      }
      #pragma unroll
      for (int sh=0; sh<2; sh++){
        #pragma unroll
        for (int dt=0; dt<2; dt++){
          bf16x8 vfr = *(const bf16x8*)(Vtb + (size_t)(dt*32+lr)*2048 + s0 + sh*16 + 8*hi);
          oacc[dt] = __builtin_amdgcn_mfma_f32_32x32x16_bf16(af[sh], vfr, oacc[dt], 0,0,0);
        }
      }
      if (!half){ unsigned short* tmp = cur; cur = prv; prv = tmp; }
    }
  }

  // store attn output rows (bf16)
  unsigned short* Obase = attn_o + ((size_t)bh*2048 + l0w)*64;
  #pragma unroll
  for (int dt=0; dt<2; dt++)
    #pragma unroll
    for (int g=0; g<16; g++){
      const int rp = ROWPAT(g,hi);
      Obase[(size_t)rp*64 + dt*32 + lr] = f2bf(oacc[dt][g]);
    }
}

// ---------------- K3: out(8192x512 fp32) = attn_gathered(bf16) @ fc_w + fc_b ----------------
__global__ __launch_bounds__(256,2) void fc_gemm_kernel(
    const unsigned short* __restrict__ A,
    const unsigned int* __restrict__ Wt,
    const float* __restrict__ bias, float* __restrict__ Out)
{
  __shared__ unsigned int Al[128][17];
  __shared__ unsigned int Bl[128][17];
  const int n0 = blockIdx.x * 128;
  const int m0 = blockIdx.y * 128;
  const int tid = threadIdx.x;
  const int lane = tid & 63, wave = tid >> 6;
  const int lr = lane & 31, hi = lane >> 5;
  const int wr = wave >> 1, wc = wave & 1;
  const int r = tid & 127, kh = tid >> 7;

  f32x16 acc[2][2];
  acc[0][0]=zero16(); acc[0][1]=zero16(); acc[1][0]=zero16(); acc[1][1]=zero16();

  for (int k0=0; k0<512; k0+=32){
    const int m = m0 + r; const int b = m >> 11, l = m & 2047;
    const int k = k0 + kh*16; const int h = k >> 6, dh0 = k & 63;
    const unsigned int* Ar = (const unsigned int*)(A + ((size_t)(b*8+h)*2048 + l)*64 + dh0);
    #pragma unroll
    for (int c=0;c<8;c++) Al[r][kh*8+c] = Ar[c];
    const unsigned int* Wr = Wt + (size_t)(n0 + r)*256 + (k0>>1) + kh*8;
    #pragma unroll
    for (int c=0;c<8;c++) Bl[r][kh*8 + c] = Wr[c];
    __syncthreads();
    #pragma unroll
    for (int t=0;t<2;t++){
      bf16x8 af[2], bfr[2];
      #pragma unroll
      for (int mt=0;mt<2;mt++){
        u32x4 w;
        #pragma unroll
        for (int j=0;j<4;j++) w[j] = Al[wr*64 + mt*32 + lr][t*8 + hi*4 + j];
        af[mt] = __builtin_bit_cast(bf16x8, w);
      }
      #pragma unroll
      for (int nt=0;nt<2;nt++){
        u32x4 w;
        #pragma unroll
        for (int j=0;j<4;j++) w[j] = Bl[wc*64 + nt*32 + lr][t*8 + hi*4 + j];
        bfr[nt] = __builtin_bit_cast(bf16x8, w);
      }
      #pragma unroll
      for (int mt=0;mt<2;mt++)
        #pragma unroll
        for (int nt=0;nt<2;nt++)
          acc[mt][nt] = __builtin_amdgcn_mfma_f32_32x32x16_bf16(af[mt], bfr[nt], acc[mt][nt], 0,0,0);
    }
    __syncthreads();
  }

  #pragma unroll
  for (int mt=0;mt<2;mt++)
    #pragma unroll
    for (int nt=0;nt<2;nt++){
      const int n = n0 + wc*64 + nt*32 + lr;
      const float bv = bias[n];
      #pragma unroll
      for (int g=0; g<16; g++){
        const int m2 = m0 + wr*64 + mt*32 + ROWPAT(g,hi);
        Out[(size_t)m2*512 + n] = acc[mt][nt][g] + bv;
      }
    }
}

extern "C" void kernel_launch(void* const* d_in, const int* in_sizes, int n_in,
                              void* d_out, int out_size, void* d_ws, size_t ws_size,
                              hipStream_t stream)
{
  const float* q_in = (const float*)d_in[0];
  const float* k_in = (const float*)d_in[1];
  const float* v_in = (const float*)d_in[2];
  const float* Wq_w = (const float*)d_in[3];
  const float* Wq_b = (const float*)d_in[4];
  const float* Wk_w = (const float*)d_in[5];
  const float* Wk_b = (const float*)d_in[6];
  const float* Wv_w = (const float*)d_in[7];
  const float* Wv_b = (const float*)d_in[8];
  const float* E    = (const float*)d_in[9];
  const float* fc_w = (const float*)d_in[10];
  const float* fc_b = (const float*)d_in[11];

  float* out = (float*)d_out;
  float* attn_w = out + (size_t)4*2048*512;

  unsigned short* Qws = (unsigned short*)d_ws;          // 4194304 elems each
  unsigned short* Kws = Qws + (size_t)4194304;
  unsigned short* Vws = Kws + (size_t)4194304;
  unsigned short* ATT = Vws + (size_t)4194304;
  unsigned short* VTs = ATT + (size_t)4194304;
  unsigned short* Ebf = VTs + (size_t)4194304;          // 131072 elems
  unsigned short* WqT = Ebf + 131072;
  unsigned short* WkT = WqT + 262144;
  unsigned short* WvT = WkT + 262144;
  unsigned short* WfT = WvT + 262144;

  dim3 tg(16,16);
  hipLaunchKernelGGL(transpose_w_kernel, tg, dim3(256), 0, stream, Wq_w, WqT);
  hipLaunchKernelGGL(transpose_w_kernel, tg, dim3(256), 0, stream, Wk_w, WkT);
  hipLaunchKernelGGL(transpose_w_kernel, tg, dim3(256), 0, stream, Wv_w, WvT);
  hipLaunchKernelGGL(transpose_w_kernel, tg, dim3(256), 0, stream, fc_w, WfT);
  hipLaunchKernelGGL(erev_kernel, dim3(128), dim3(256), 0, stream, E, Ebf);

  dim3 pg(4, 64);
  hipLaunchKernelGGL(proj_gemm_kernel, pg, dim3(256), 0, stream, q_in, (const unsigned int*)WqT, Wq_b, Qws);
  hipLaunchKernelGGL(proj_gemm_kernel, pg, dim3(256), 0, stream, k_in, (const unsigned int*)WkT, Wk_b, Kws);
  hipLaunchKernelGGL(proj_gemm_kernel, pg, dim3(256), 0, stream, v_in, (const unsigned int*)WvT, Wv_b, Vws);

  hipLaunchKernelGGL(transpose_v_kernel, dim3(64,2,32), dim3(256), 0, stream, Vws, VTs);

  hipLaunchKernelGGL(attn_kernel, dim3(16,32), dim3(256), 0, stream, Qws, Kws, VTs, Ebf, attn_w, ATT);

  hipLaunchKernelGGL(fc_gemm_kernel, pg, dim3(256), 0, stream, ATT, (const unsigned int*)WfT, fc_b, out);
}